// Round 15
// baseline (663.774 us; speedup 1.0000x reference)
//
// Round 15: single-hop stamped exchange. Each published 8B chunk = {2 bf16 h
// values, u32 stamp=t+1} stored atomically (dwordx2). Readers poll their OWN
// chunks: detect == readback (one IC hop). No flags, no drains, no SA barrier.
// Monotonic stamps (no re-init). Parity-buffered LDS tiles -> 1 barrier/step.
// Compute/publish/readback decomposition identical to r12 (best, 246us).
#include <hip/hip_runtime.h>

typedef unsigned short u16;
typedef unsigned int   u32;
typedef unsigned long long u64;
typedef __attribute__((ext_vector_type(8))) short bf16x8;  // 8 bf16 (4 VGPRs)
typedef __attribute__((ext_vector_type(4))) float f32x4;   // MFMA C/D frag

#define DEVINL static __device__ __forceinline__
#define MFMA __builtin_amdgcn_mfma_f32_16x16x32_bf16

DEVINL u16 f2bf(float f){ u32 x = __float_as_uint(f); return (u16)((x + 0x7fffu + ((x>>16)&1u)) >> 16); }
DEVINL float bf2f(u16 u){ return __uint_as_float(((u32)u) << 16); }
DEVINL u32 pack2(float a, float b){ return (u32)f2bf(a) | ((u32)f2bf(b) << 16); }
DEVINL float sigm(float x){ return 1.f/(1.f + __expf(-x)); }
DEVINL float tanhs(float x){ float xc = fminf(fmaxf(x,-15.f),15.f); float e = __expf(2.f*xc); return (e-1.f)/(e+1.f); }
DEVINL void g_store64(u64* p, u64 v){ __hip_atomic_store(p, v, __ATOMIC_RELAXED, __HIP_MEMORY_SCOPE_AGENT); }
DEVINL u64  g_load64(const u64* p){ return __hip_atomic_load(p, __ATOMIC_RELAXED, __HIP_MEMORY_SCOPE_AGENT); }

// ---------------- prep: pack weights to bf16 with row permutation j' = u*4+gate
// matrix order m: 0 eIH_l0, 1 eHH_l0, 2 eIH_l1, 3 eHH_l1, 4 dIH_l0, 5 dHH_l0, 6 dIH_l1, 7 dHH_l1
__global__ void pack_all(const float* __restrict__ eih, const float* __restrict__ ehh,
                         const float* __restrict__ dih, const float* __restrict__ dhh,
                         const float* __restrict__ ebi, const float* __restrict__ ebh,
                         const float* __restrict__ dbi, const float* __restrict__ dbh,
                         u16* __restrict__ wout, float* __restrict__ bout,
                         u32* __restrict__ Hz){
  int blk = blockIdx.x, t = threadIdx.x;
  if (blk < 8192){
    int m = blk >> 10, j2 = blk & 1023;
    const float* base = (m < 4) ? ((m & 1) ? ehh : eih) : ((m & 1) ? dhh : dih);
    const float* S = base + (size_t)((m >> 1) & 1) * 262144;  // layer select
    int u = j2 >> 2, g = j2 & 3, j = g*256 + u;
    wout[(size_t)blk*256 + t] = f2bf(S[(size_t)j*256 + t]);
  } else if (blk < 8208){
    int idx = (blk - 8192)*256 + t;             // 0..4095 : [phase][layer][j']
    int phase = idx >> 11, l = (idx >> 10) & 1, j2 = idx & 1023;
    int u = j2 >> 2, g = j2 & 3, j = g*256 + u;
    const float* bi = phase ? dbi : ebi;
    const float* bh = phase ? dbh : ebh;
    bout[idx] = bi[l*1024 + j] + bh[l*1024 + j];
  } else {
    int idx = (blk - 8208)*256 + t;             // zero stamps (H1c+H2c = 2MB)
    Hz[idx] = 0u;                               // re-zeroed EVERY call
  }
}

struct SM {
  u16   X[2][16][264];    // x(t) by parity
  u16   H1t[2][16][264];  // h1 by parity
  u16   H2t[2][16][264];  // h2 by parity
  float fcw[4][256];
  float fcb[4];
  int   tok[63][16];
};

__global__ void __launch_bounds__(512, 2)
lstm_main(const int* __restrict__ src, const float* __restrict__ enc_emb,
          const float* __restrict__ dec_emb, const u16* __restrict__ wpack,
          const float* __restrict__ bpack, const float* __restrict__ fcW,
          const float* __restrict__ fcb, float* __restrict__ out,
          u64* __restrict__ H1c, u64* __restrict__ H2c)
{
  __shared__ SM sm;
  const int tid  = threadIdx.x;
  const int wv   = tid >> 6;          // wave 0..7
  const int lane = tid & 63;
  const int agrp = lane >> 4;         // k-group
  const int n    = lane & 15;         // batch row
  const int gid  = blockIdx.x & 31;   // batch group (same XCD across slices)
  const int w    = blockIdx.x >> 5;   // column-slice 0..7
  const int wgb0 = gid << 4;
  const int xr   = tid >> 5, xk = (tid & 31) << 3;     // x-gather: row, u16-col
  const int myl  = wv >> 2;           // 0: layer1-wave, 1: layer2-wave
  const int wq   = wv & 3;            // quarter within role
  const bool pub = (agrp & 1) == 0;
  const int jrow0 = (w << 7) + (wq << 5) + n;          // gate row j', tile ct=0
  const int jrow1 = jrow0 + 16;                        // tile ct=1
  const int uu0   = (w << 5) + (wq << 3) + agrp;       // unit, tile ct=0
  const int uu1   = uu0 + 4;
  const int pw0   = (w << 4) + (wq << 2) + (agrp >> 1);// chunk index, tile ct=0
  const int pw1   = pw0 + 2;

  // ---- prologue staging
  for (int i = tid; i < 1008; i += 512){
    int s = i >> 4, b = i & 15;
    int t = (s < 31) ? (31 - s) : (s - 31);   // enc reversed, then dec forward
    sm.tok[s][b] = src[t*512 + wgb0 + b];
  }
  for (int i = tid; i < 1024; i += 512) ((float*)sm.fcw)[i] = fcW[i];
  if (tid < 4) sm.fcb[tid] = fcb[tid];
  for (int i = tid; i < 2112; i += 512){      // zero parity-0 h tiles
    ((u32*)sm.H1t[0])[i] = 0u;
    ((u32*)sm.H2t[0])[i] = 0u;
  }
  __syncthreads();
  { // x(0) -> X[0]
    int tk = sm.tok[0][xr];
    const float* e = enc_emb + (size_t)tk*256 + xk;
    float4 v0 = *(const float4*)e, v1 = *(const float4*)(e + 4);
    u32* d = (u32*)&sm.X[0][xr][xk];
    d[0]=pack2(v0.x,v0.y); d[1]=pack2(v0.z,v0.w); d[2]=pack2(v1.x,v1.y); d[3]=pack2(v1.z,v1.w);
  }
  float4 xh0, xh1;                            // x(t+1) held in regs
  { // issue x(1)
    int tk = sm.tok[1][xr];
    const float* e = enc_emb + (size_t)tk*256 + xk;
    xh0 = *(const float4*)e; xh1 = *(const float4*)(e + 4);
  }

  // ---- weight-stationary: my layer's 2 gate-tiles, W[2][16] = 128 regs
  bf16x8 W[2][16];
  float4 br[2];
  float  cst[2] = {0.f, 0.f};

  auto LOADW = [&](int ph){
    const u16* base = wpack + (size_t)ph*1048576 + (size_t)myl*524288;
    #pragma unroll
    for (int kk = 0; kk < 16; kk++){
      const size_t moff = (size_t)(kk >> 3)*262144 + ((kk & 7) << 5) + (agrp << 3);
      W[0][kk] = *(const bf16x8*)(base + moff + (size_t)jrow0*256);
      W[1][kk] = *(const bf16x8*)(base + moff + (size_t)jrow1*256);
    }
    br[0] = *(const float4*)(bpack + (((ph << 1) + myl) << 10) + (uu0 << 2));
    br[1] = *(const float4*)(bpack + (((ph << 1) + myl) << 10) + (uu1 << 2));
  };
  LOADW(0);
  __syncthreads();

  auto step = [&](int t){
    const int par = t & 1, parW = par ^ 1;
    // ---- compute my layer: l1(t) waves 0-3; l2(t-1) waves 4-7
    const bool active = myl ? (t >= 1) : (t <= 62);
    if (active){
      const u16 (*loT)[264] = myl ? sm.H1t[par] : sm.X[par];   // l1: x(t);   l2: h1(t-1)
      const u16 (*hiT)[264] = myl ? sm.H2t[par] : sm.H1t[par]; // l1: h1(t-1); l2: h2(t-2)
      f32x4 a0 = {0.f,0.f,0.f,0.f}, a1 = {0.f,0.f,0.f,0.f};
      #pragma unroll
      for (int kk = 0; kk < 8; kk++){
        bf16x8 b = *(const bf16x8*)&loT[n][(kk << 5) + (agrp << 3)];
        a0 = MFMA(W[0][kk], b, a0, 0, 0, 0);
        a1 = MFMA(W[1][kk], b, a1, 0, 0, 0);
      }
      #pragma unroll
      for (int kk = 0; kk < 8; kk++){
        bf16x8 b = *(const bf16x8*)&hiT[n][(kk << 5) + (agrp << 3)];
        a0 = MFMA(W[0][8 + kk], b, a0, 0, 0, 0);
        a1 = MFMA(W[1][8 + kk], b, a1, 0, 0, 0);
      }
      float I0 = sigm(a0[0] + br[0].x), F0 = sigm(a0[1] + br[0].y);
      float G0 = tanhs(a0[2] + br[0].z), O0 = sigm(a0[3] + br[0].w);
      float cn0 = F0*cst[0] + I0*G0; cst[0] = cn0;
      u16 h0 = f2bf(O0 * tanhs(cn0));
      float I1 = sigm(a1[0] + br[1].x), F1 = sigm(a1[1] + br[1].y);
      float G1 = tanhs(a1[2] + br[1].z), O1 = sigm(a1[3] + br[1].w);
      float cn1 = F1*cst[1] + I1*G1; cst[1] = cn1;
      u16 h1b = f2bf(O1 * tanhs(cn1));
      u32 o0 = (u32)__shfl_xor((int)(u32)h0, 16);
      u32 o1 = (u32)__shfl_xor((int)(u32)h1b, 16);
      const int ppar = myl ? ((t + 1) & 1) : par;   // l2 publishes h2(t-1)
      u64* Hp = (myl ? H2c : H1c) + (((size_t)ppar*32 + gid)*16 + n)*128;
      if (pub){                      // stamped chunk: {2 bf16 | stamp} atomic 8B
        const u64 stamp = (u64)(u32)(t + 1) << 32;
        g_store64(Hp + pw0, (u64)((u32)h0  | (o0 << 16)) | stamp);
        g_store64(Hp + pw1, (u64)((u32)h1b | (o1 << 16)) | stamp);
      }
    }
    // ---- fc on wave 1 (reads H2t[par] = h2(t-2); publish already issued)
    if (wv == 1 && t >= 33){
      const int b = (w << 1) + (lane >> 5), v = (lane >> 3) & 3, q8 = lane & 7;
      const u16* hrow = &sm.H2t[par][b][q8 << 5];
      const float* wr = &sm.fcw[v][q8 << 5];
      float s = 0.f;
      #pragma unroll
      for (int f = 0; f < 4; f++){
        bf16x8 hv = *(const bf16x8*)(hrow + (f << 3));
        const float4 wa = *(const float4*)(wr + (f << 3));
        const float4 wb = *(const float4*)(wr + (f << 3) + 4);
        s += bf2f((u16)hv[0])*wa.x + bf2f((u16)hv[1])*wa.y
           + bf2f((u16)hv[2])*wa.z + bf2f((u16)hv[3])*wa.w
           + bf2f((u16)hv[4])*wb.x + bf2f((u16)hv[5])*wb.y
           + bf2f((u16)hv[6])*wb.z + bf2f((u16)hv[7])*wb.w;
      }
      s += __shfl_xor(s, 1); s += __shfl_xor(s, 2); s += __shfl_xor(s, 4);
      s += sm.fcb[v];
      float m = fmaxf(s, __shfl_xor(s, 8)); m = fmaxf(m, __shfl_xor(m, 16));
      float e_ = __expf(s - m);
      float es = e_ + __shfl_xor(e_, 8); es += __shfl_xor(es, 16);
      if (q8 == 0)
        out[((size_t)(t - 33)*512 + wgb0 + b)*4 + v] = s - m - __logf(es);
    }
    // ---- poll-readback OWN chunks: detect == read (single IC hop)
    const int q = tid << 2;            // 4 chunks/thread
    const int r = tid >> 5, p = q & 127;
    const u32 st = (u32)(t + 1);
    if (t < 63){
      const u64* h1r = H1c + ((size_t)par*32 + gid)*2048 + q;
      u64 a0, a1, a2, a3;
      for (;;){
        a0 = g_load64(h1r+0); a1 = g_load64(h1r+1);
        a2 = g_load64(h1r+2); a3 = g_load64(h1r+3);
        if ((u32)(a0>>32)==st && (u32)(a1>>32)==st &&
            (u32)(a2>>32)==st && (u32)(a3>>32)==st) break;
        __builtin_amdgcn_s_sleep(1);
      }
      u32* d1 = (u32*)&sm.H1t[parW][r][p << 1];
      d1[0]=(u32)a0; d1[1]=(u32)a1; d1[2]=(u32)a2; d1[3]=(u32)a3;
    }
    if (t >= 1){
      const u64* h2r = H2c + ((size_t)((t - 1) & 1)*32 + gid)*2048 + q;
      u64 b0, b1, b2, b3;
      for (;;){
        b0 = g_load64(h2r+0); b1 = g_load64(h2r+1);
        b2 = g_load64(h2r+2); b3 = g_load64(h2r+3);
        if ((u32)(b0>>32)==st && (u32)(b1>>32)==st &&
            (u32)(b2>>32)==st && (u32)(b3>>32)==st) break;
        __builtin_amdgcn_s_sleep(1);
      }
      u32* d2 = (u32*)&sm.H2t[parW][r][p << 1];
      d2[0]=(u32)b0; d2[1]=(u32)b1; d2[2]=(u32)b2; d2[3]=(u32)b3;
    }
    // ---- x pipeline: x(t+1) regs -> X[parW]; issue x(t+2)
    if (t + 1 < 63){
      u32* d = (u32*)&sm.X[parW][xr][xk];
      d[0]=pack2(xh0.x,xh0.y); d[1]=pack2(xh0.z,xh0.w);
      d[2]=pack2(xh1.x,xh1.y); d[3]=pack2(xh1.z,xh1.w);
    }
    if (t + 2 < 63){
      int tk = sm.tok[t+2][xr];
      const float* e = ((t+2) < 31 ? enc_emb : dec_emb) + (size_t)tk*256 + xk;
      xh0 = *(const float4*)e; xh1 = *(const float4*)(e + 4);
    }
    __syncthreads();                          // the ONLY barrier per step
  };

  for (int t = 0; t <= 30; ++t) step(t);
  if (myl == 0) LOADW(1);   // dec W1 (first used by l1(31)); l2(30) still enc W2
  step(31);
  if (myl == 1) LOADW(1);   // dec W2 (first used computing l2(31) at step 32)
  for (int t = 32; t <= 63; ++t) step(t);

  // ---- tail fc: h2(62) (in H2t[0] after step 63's readback) -> out row 31
  if (wv == 1){
    const int b = (w << 1) + (lane >> 5), v = (lane >> 3) & 3, q8 = lane & 7;
    const u16* hrow = &sm.H2t[0][b][q8 << 5];
    const float* wr = &sm.fcw[v][q8 << 5];
    float s = 0.f;
    #pragma unroll
    for (int f = 0; f < 4; f++){
      bf16x8 hv = *(const bf16x8*)(hrow + (f << 3));
      const float4 wa = *(const float4*)(wr + (f << 3));
      const float4 wb = *(const float4*)(wr + (f << 3) + 4);
      s += bf2f((u16)hv[0])*wa.x + bf2f((u16)hv[1])*wa.y
         + bf2f((u16)hv[2])*wa.z + bf2f((u16)hv[3])*wa.w
         + bf2f((u16)hv[4])*wb.x + bf2f((u16)hv[5])*wb.y
         + bf2f((u16)hv[6])*wb.z + bf2f((u16)hv[7])*wb.w;
    }
    s += __shfl_xor(s, 1); s += __shfl_xor(s, 2); s += __shfl_xor(s, 4);
    s += sm.fcb[v];
    float m = fmaxf(s, __shfl_xor(s, 8)); m = fmaxf(m, __shfl_xor(m, 16));
    float e_ = __expf(s - m);
    float es = e_ + __shfl_xor(e_, 8); es += __shfl_xor(es, 16);
    if (q8 == 0)
      out[((size_t)31*512 + wgb0 + b)*4 + v] = s - m - __logf(es);
  }
}

extern "C" void kernel_launch(void* const* d_in, const int* in_sizes, int n_in,
                              void* d_out, int out_size, void* d_ws, size_t ws_size,
                              hipStream_t stream){
  const int*   src     = (const int*)  d_in[0];
  const float* enc_emb = (const float*)d_in[2];
  const float* enc_Wih = (const float*)d_in[3];
  const float* enc_Whh = (const float*)d_in[4];
  const float* enc_bih = (const float*)d_in[5];
  const float* enc_bhh = (const float*)d_in[6];
  const float* dec_emb = (const float*)d_in[7];
  const float* dec_Wih = (const float*)d_in[8];
  const float* dec_Whh = (const float*)d_in[9];
  const float* dec_bih = (const float*)d_in[10];
  const float* dec_bhh = (const float*)d_in[11];
  const float* fcW     = (const float*)d_in[12];
  const float* fcb     = (const float*)d_in[13];
  float* out = (float*)d_out;
  (void)in_sizes; (void)n_in; (void)out_size; (void)ws_size;

  // ws: wpack 4MB | bpack 16KB | H1c 1MB (stamped, 2-parity) | H2c 1MB
  u16*   wpack = (u16*)d_ws;
  float* bpack = (float*)((char*)d_ws + 4194304);
  u64*   H1c   = (u64*)((char*)d_ws + 4194304 + 16384);
  u64*   H2c   = H1c + 131072;
  u32*   Hz    = (u32*)H1c;           // 2MB zeroed by prep (stamps reset)

  pack_all<<<10256, 256, 0, stream>>>(enc_Wih, enc_Whh, dec_Wih, dec_Whh,
                                      enc_bih, enc_bhh, dec_bih, dec_bhh,
                                      wpack, bpack, Hz);
  lstm_main<<<256, 512, 0, stream>>>(src, enc_emb, dec_emb, wpack, bpack,
                                     fcW, fcb, out, H1c, H2c);
}

// Round 16
// 222.034 us; speedup vs baseline: 2.9895x; 2.9895x over previous
//
// Round 16: r12 restored (best, 246us) with ONE micro-fix: readback uses u64
// agent-scope atomic loads (2/thread instead of 4 u32) — same bytes, half the
// IC load count. Protocol unchanged: SA barrier + tid0 single flag store +
// wave0-only 8-lane poll; wave1 full-wave fc in poll slack; x(t+2) reg lookahead.
// Wave-specialized layers (r8): waves 0-3 l1, 4-7 l2, W[2][16]=128 VGPR.
#include <hip/hip_runtime.h>

typedef unsigned short u16;
typedef unsigned int   u32;
typedef unsigned long long u64;
typedef __attribute__((ext_vector_type(8))) short bf16x8;  // 8 bf16 (4 VGPRs)
typedef __attribute__((ext_vector_type(4))) float f32x4;   // MFMA C/D frag

#define DEVINL static __device__ __forceinline__
#define MFMA __builtin_amdgcn_mfma_f32_16x16x32_bf16

DEVINL u16 f2bf(float f){ u32 x = __float_as_uint(f); return (u16)((x + 0x7fffu + ((x>>16)&1u)) >> 16); }
DEVINL float bf2f(u16 u){ return __uint_as_float(((u32)u) << 16); }
DEVINL u32 pack2(float a, float b){ return (u32)f2bf(a) | ((u32)f2bf(b) << 16); }
DEVINL float sigm(float x){ return 1.f/(1.f + __expf(-x)); }
DEVINL float tanhs(float x){ float xc = fminf(fmaxf(x,-15.f),15.f); float e = __expf(2.f*xc); return (e-1.f)/(e+1.f); }
DEVINL void g_store(u32* p, u32 v){ __hip_atomic_store(p, v, __ATOMIC_RELAXED, __HIP_MEMORY_SCOPE_AGENT); }
DEVINL u32  g_load(const u32* p){ return __hip_atomic_load(p, __ATOMIC_RELAXED, __HIP_MEMORY_SCOPE_AGENT); }
DEVINL u64  g_load64(const u64* p){ return __hip_atomic_load(p, __ATOMIC_RELAXED, __HIP_MEMORY_SCOPE_AGENT); }

// ---------------- prep: pack weights to bf16 with row permutation j' = u*4+gate
// matrix order m: 0 eIH_l0, 1 eHH_l0, 2 eIH_l1, 3 eHH_l1, 4 dIH_l0, 5 dHH_l0, 6 dIH_l1, 7 dHH_l1
__global__ void pack_all(const float* __restrict__ eih, const float* __restrict__ ehh,
                         const float* __restrict__ dih, const float* __restrict__ dhh,
                         const float* __restrict__ ebi, const float* __restrict__ ebh,
                         const float* __restrict__ dbi, const float* __restrict__ dbh,
                         u16* __restrict__ wout, float* __restrict__ bout,
                         u32* __restrict__ flags){
  int blk = blockIdx.x, t = threadIdx.x;
  if (blk < 8192){
    int m = blk >> 10, j2 = blk & 1023;
    const float* base = (m < 4) ? ((m & 1) ? ehh : eih) : ((m & 1) ? dhh : dih);
    const float* S = base + (size_t)((m >> 1) & 1) * 262144;  // layer select
    int u = j2 >> 2, g = j2 & 3, j = g*256 + u;
    wout[(size_t)blk*256 + t] = f2bf(S[(size_t)j*256 + t]);
  } else if (blk < 8208){
    int idx = (blk - 8192)*256 + t;             // 0..4095 : [phase][layer][j']
    int phase = idx >> 11, l = (idx >> 10) & 1, j2 = idx & 1023;
    int u = j2 >> 2, g = j2 & 3, j = g*256 + u;
    const float* bi = phase ? dbi : ebi;
    const float* bh = phase ? dbh : ebh;
    bout[idx] = bi[l*1024 + j] + bh[l*1024 + j];
  } else {
    for (int i = t; i < 2048; i += 256) flags[i] = 0u;   // flag reset EVERY call
  }
}

struct SM {
  u16   X[16][264];       // x(t)
  u16   H1t[16][264];     // h1(t-1) at compute time
  u16   H2t[16][264];     // h2(t-2) at compute time; h2(t-1) after readback
  float fcw[4][256];
  float fcb[4];
  int   tok[63][16];
};

__global__ void __launch_bounds__(512, 2)
lstm_main(const int* __restrict__ src, const float* __restrict__ enc_emb,
          const float* __restrict__ dec_emb, const u16* __restrict__ wpack,
          const float* __restrict__ bpack, const float* __restrict__ fcW,
          const float* __restrict__ fcb, float* __restrict__ out,
          u32* __restrict__ H1, u32* __restrict__ H2, u32* __restrict__ flags)
{
  __shared__ SM sm;
  const int tid  = threadIdx.x;
  const int wv   = tid >> 6;          // wave 0..7
  const int lane = tid & 63;
  const int agrp = lane >> 4;         // k-group
  const int n    = lane & 15;         // batch row
  const int gid  = blockIdx.x & 31;   // batch group (same XCD across slices)
  const int w    = blockIdx.x >> 5;   // column-slice 0..7
  const int wgb0 = gid << 4;
  const int xr   = tid >> 5, xk = (tid & 31) << 3;     // x-gather: row, u16-col
  const int myl  = wv >> 2;           // 0: layer1-wave, 1: layer2-wave
  const int wq   = wv & 3;            // quarter within role
  const bool pub = (agrp & 1) == 0;
  const int jrow0 = (w << 7) + (wq << 5) + n;          // gate row j', tile ct=0
  const int jrow1 = jrow0 + 16;                        // tile ct=1
  const int uu0   = (w << 5) + (wq << 3) + agrp;       // unit, tile ct=0
  const int uu1   = uu0 + 4;
  const int pw0   = (w << 4) + (wq << 2) + (agrp >> 1);// u32 word, tile ct=0
  const int pw1   = pw0 + 2;

  // ---- prologue staging
  for (int i = tid; i < 1008; i += 512){
    int s = i >> 4, b = i & 15;
    int t = (s < 31) ? (31 - s) : (s - 31);   // enc reversed, then dec forward
    sm.tok[s][b] = src[t*512 + wgb0 + b];
  }
  for (int i = tid; i < 1024; i += 512) ((float*)sm.fcw)[i] = fcW[i];
  if (tid < 4) sm.fcb[tid] = fcb[tid];
  for (int i = tid; i < 2112; i += 512){      // zero h tiles
    ((u32*)sm.H1t)[i] = 0u;
    ((u32*)sm.H2t)[i] = 0u;
  }
  __syncthreads();
  { // x(0) -> X
    int tk = sm.tok[0][xr];
    const float* e = enc_emb + (size_t)tk*256 + xk;
    float4 v0 = *(const float4*)e, v1 = *(const float4*)(e + 4);
    u32* d = (u32*)&sm.X[xr][xk];
    d[0]=pack2(v0.x,v0.y); d[1]=pack2(v0.z,v0.w); d[2]=pack2(v1.x,v1.y); d[3]=pack2(v1.z,v1.w);
  }
  float4 xh0, xh1;                            // x(t+1) held in regs
  { // issue x(1)
    int tk = sm.tok[1][xr];
    const float* e = enc_emb + (size_t)tk*256 + xk;
    xh0 = *(const float4*)e; xh1 = *(const float4*)(e + 4);
  }

  // ---- weight-stationary: my layer's 2 gate-tiles, W[2][16] = 128 regs
  bf16x8 W[2][16];
  float4 br[2];
  float  cst[2] = {0.f, 0.f};

  auto LOADW = [&](int ph){
    const u16* base = wpack + (size_t)ph*1048576 + (size_t)myl*524288;
    #pragma unroll
    for (int kk = 0; kk < 16; kk++){
      const size_t moff = (size_t)(kk >> 3)*262144 + ((kk & 7) << 5) + (agrp << 3);
      W[0][kk] = *(const bf16x8*)(base + moff + (size_t)jrow0*256);
      W[1][kk] = *(const bf16x8*)(base + moff + (size_t)jrow1*256);
    }
    br[0] = *(const float4*)(bpack + (((ph << 1) + myl) << 10) + (uu0 << 2));
    br[1] = *(const float4*)(bpack + (((ph << 1) + myl) << 10) + (uu1 << 2));
  };
  LOADW(0);
  __syncthreads();

  auto step = [&](int t){
    // ---- compute my layer: l1(t) waves 0-3; l2(t-1) waves 4-7
    const bool active = myl ? (t >= 1) : (t <= 62);
    if (active){
      const u16 (*loT)[264] = myl ? sm.H1t : sm.X;    // l1: x(t)   ; l2: h1(t-1)
      const u16 (*hiT)[264] = myl ? sm.H2t : sm.H1t;  // l1: h1(t-1); l2: h2(t-2)
      f32x4 a0 = {0.f,0.f,0.f,0.f}, a1 = {0.f,0.f,0.f,0.f};
      #pragma unroll
      for (int kk = 0; kk < 8; kk++){
        bf16x8 b = *(const bf16x8*)&loT[n][(kk << 5) + (agrp << 3)];
        a0 = MFMA(W[0][kk], b, a0, 0, 0, 0);
        a1 = MFMA(W[1][kk], b, a1, 0, 0, 0);
      }
      #pragma unroll
      for (int kk = 0; kk < 8; kk++){
        bf16x8 b = *(const bf16x8*)&hiT[n][(kk << 5) + (agrp << 3)];
        a0 = MFMA(W[0][8 + kk], b, a0, 0, 0, 0);
        a1 = MFMA(W[1][8 + kk], b, a1, 0, 0, 0);
      }
      float I0 = sigm(a0[0] + br[0].x), F0 = sigm(a0[1] + br[0].y);
      float G0 = tanhs(a0[2] + br[0].z), O0 = sigm(a0[3] + br[0].w);
      float cn0 = F0*cst[0] + I0*G0; cst[0] = cn0;
      u16 h0 = f2bf(O0 * tanhs(cn0));
      float I1 = sigm(a1[0] + br[1].x), F1 = sigm(a1[1] + br[1].y);
      float G1 = tanhs(a1[2] + br[1].z), O1 = sigm(a1[3] + br[1].w);
      float cn1 = F1*cst[1] + I1*G1; cst[1] = cn1;
      u16 h1b = f2bf(O1 * tanhs(cn1));
      u32 o0 = (u32)__shfl_xor((int)(u32)h0, 16);
      u32 o1 = (u32)__shfl_xor((int)(u32)h1b, 16);
      const int ppar = myl ? ((t + 1) & 1) : (t & 1);   // l2 publishes h2(t-1)
      u32* Hp = (myl ? H2 : H1) + ((size_t)ppar*32 + gid)*2048 + n*128;
      if (pub){
        g_store(Hp + pw0, (u32)h0 | (o0 << 16));
        g_store(Hp + pw1, (u32)h1b | (o1 << 16));
      }
    }
    __syncthreads();                                           // SA: stores drained
    if (tid == 0) g_store(&flags[gid*8 + w], (u32)(t + 1));
    // ---- poll slack: wave0 polls; wave1 does fc for h2(t-2) -> out row t-33
    if (wv == 0){
      const u32 tgt = (u32)(t + 1);
      const bool mine = lane < 8;
      for (;;){
        u32 v = mine ? g_load(&flags[gid*8 + lane]) : tgt;
        if (__all(v >= tgt)) break;
        __builtin_amdgcn_s_sleep(1);
      }
    } else if (wv == 1 && t >= 33){
      const int b = (w << 1) + (lane >> 5), v = (lane >> 3) & 3, q8 = lane & 7;
      const u16* hrow = &sm.H2t[b][q8 << 5];
      const float* wr = &sm.fcw[v][q8 << 5];
      float s = 0.f;
      #pragma unroll
      for (int f = 0; f < 4; f++){
        bf16x8 hv = *(const bf16x8*)(hrow + (f << 3));
        const float4 wa = *(const float4*)(wr + (f << 3));
        const float4 wb = *(const float4*)(wr + (f << 3) + 4);
        s += bf2f((u16)hv[0])*wa.x + bf2f((u16)hv[1])*wa.y
           + bf2f((u16)hv[2])*wa.z + bf2f((u16)hv[3])*wa.w
           + bf2f((u16)hv[4])*wb.x + bf2f((u16)hv[5])*wb.y
           + bf2f((u16)hv[6])*wb.z + bf2f((u16)hv[7])*wb.w;
      }
      s += __shfl_xor(s, 1); s += __shfl_xor(s, 2); s += __shfl_xor(s, 4);
      s += sm.fcb[v];
      float m = fmaxf(s, __shfl_xor(s, 8)); m = fmaxf(m, __shfl_xor(m, 16));
      float e_ = __expf(s - m);
      float es = e_ + __shfl_xor(e_, 8); es += __shfl_xor(es, 16);
      if (q8 == 0)
        out[((size_t)(t - 33)*512 + wgb0 + b)*4 + v] = s - m - __logf(es);
    }
    __syncthreads();                                           // SC
    { // readback h1(t)/h2(t-1) -> LDS (u64 loads); x regs -> X; issue x(t+2)
      const int q2 = tid << 1, r = tid >> 5, p = (tid << 2) & 127;
      if (t < 63){
        const u64* h1r = (const u64*)(H1 + ((size_t)(t & 1)*32 + gid)*2048);
        u64 A = g_load64(h1r + q2), B = g_load64(h1r + q2 + 1);
        u32* d1 = (u32*)&sm.H1t[r][p << 1];
        d1[0]=(u32)A; d1[1]=(u32)(A >> 32); d1[2]=(u32)B; d1[3]=(u32)(B >> 32);
      }
      if (t > 0){
        const u64* h2r = (const u64*)(H2 + ((size_t)((t - 1) & 1)*32 + gid)*2048);
        u64 C = g_load64(h2r + q2), D = g_load64(h2r + q2 + 1);
        u32* d2 = (u32*)&sm.H2t[r][p << 1];
        d2[0]=(u32)C; d2[1]=(u32)(C >> 32); d2[2]=(u32)D; d2[3]=(u32)(D >> 32);
      }
      if (t + 1 < 63){                   // x(t+1) regs (loaded last step) -> X
        u32* d = (u32*)&sm.X[xr][xk];
        d[0]=pack2(xh0.x,xh0.y); d[1]=pack2(xh0.z,xh0.w);
        d[2]=pack2(xh1.x,xh1.y); d[3]=pack2(xh1.z,xh1.w);
      }
      if (t + 2 < 63){                   // issue x(t+2) into held regs
        int tk = sm.tok[t+2][xr];
        const float* e = ((t+2) < 31 ? enc_emb : dec_emb) + (size_t)tk*256 + xk;
        xh0 = *(const float4*)e; xh1 = *(const float4*)(e + 4);
      }
    }
    __syncthreads();                                           // SD
  };

  for (int t = 0; t <= 30; ++t) step(t);
  if (myl == 0) LOADW(1);   // dec W1 (first used by l1(31)); l2(30) still enc W2
  step(31);
  if (myl == 1) LOADW(1);   // dec W2 (first used computing l2(31) at step 32)
  for (int t = 32; t <= 63; ++t) step(t);

  // ---- tail fc: h2(62) (in H2t after step 63's readback) -> out row 31
  if (wv == 1){
    const int b = (w << 1) + (lane >> 5), v = (lane >> 3) & 3, q8 = lane & 7;
    const u16* hrow = &sm.H2t[b][q8 << 5];
    const float* wr = &sm.fcw[v][q8 << 5];
    float s = 0.f;
    #pragma unroll
    for (int f = 0; f < 4; f++){
      bf16x8 hv = *(const bf16x8*)(hrow + (f << 3));
      const float4 wa = *(const float4*)(wr + (f << 3));
      const float4 wb = *(const float4*)(wr + (f << 3) + 4);
      s += bf2f((u16)hv[0])*wa.x + bf2f((u16)hv[1])*wa.y
         + bf2f((u16)hv[2])*wa.z + bf2f((u16)hv[3])*wa.w
         + bf2f((u16)hv[4])*wb.x + bf2f((u16)hv[5])*wb.y
         + bf2f((u16)hv[6])*wb.z + bf2f((u16)hv[7])*wb.w;
    }
    s += __shfl_xor(s, 1); s += __shfl_xor(s, 2); s += __shfl_xor(s, 4);
    s += sm.fcb[v];
    float m = fmaxf(s, __shfl_xor(s, 8)); m = fmaxf(m, __shfl_xor(m, 16));
    float e_ = __expf(s - m);
    float es = e_ + __shfl_xor(e_, 8); es += __shfl_xor(es, 16);
    if (q8 == 0)
      out[((size_t)31*512 + wgb0 + b)*4 + v] = s - m - __logf(es);
  }
}

extern "C" void kernel_launch(void* const* d_in, const int* in_sizes, int n_in,
                              void* d_out, int out_size, void* d_ws, size_t ws_size,
                              hipStream_t stream){
  const int*   src     = (const int*)  d_in[0];
  const float* enc_emb = (const float*)d_in[2];
  const float* enc_Wih = (const float*)d_in[3];
  const float* enc_Whh = (const float*)d_in[4];
  const float* enc_bih = (const float*)d_in[5];
  const float* enc_bhh = (const float*)d_in[6];
  const float* dec_emb = (const float*)d_in[7];
  const float* dec_Wih = (const float*)d_in[8];
  const float* dec_Whh = (const float*)d_in[9];
  const float* dec_bih = (const float*)d_in[10];
  const float* dec_bhh = (const float*)d_in[11];
  const float* fcW     = (const float*)d_in[12];
  const float* fcb     = (const float*)d_in[13];
  float* out = (float*)d_out;
  (void)in_sizes; (void)n_in; (void)out_size; (void)ws_size;

  // ws: wpack 4MB | bpack 16KB | H1 512KB (2-parity) | H2 512KB | flags 8KB
  u16*   wpack = (u16*)d_ws;
  float* bpack = (float*)((char*)d_ws + 4194304);
  u32*   H1    = (u32*)((char*)d_ws + 4194304 + 16384);
  u32*   H2    = (u32*)((char*)d_ws + 4194304 + 16384 + 524288);
  u32*   flags = (u32*)((char*)d_ws + 4194304 + 16384 + 1048576);

  pack_all<<<8209, 256, 0, stream>>>(enc_Wih, enc_Whh, dec_Wih, dec_Whh,
                                     enc_bih, enc_bhh, dec_bih, dec_bhh,
                                     wpack, bpack, flags);
  lstm_main<<<256, 512, 0, stream>>>(src, enc_emb, dec_emb, wpack, bpack,
                                     fcW, fcb, out, H1, H2, flags);
}